// Round 6
// baseline (575.193 us; speedup 1.0000x reference)
//
#include <hip/hip_runtime.h>

#define TT 512
#define MM 8       // batch rows per block -> grid 512 = 2 blocks/CU

typedef _Float16 f16_t;
typedef f16_t f16x8 __attribute__((ext_vector_type(8)));
typedef float  f32x4 __attribute__((ext_vector_type(4)));

#define MFMA16(A, B, C) __builtin_amdgcn_mfma_f32_16x16x32_f16((A), (B), (C), 0, 0, 0)

__device__ __forceinline__ float fr(float x) { return __builtin_amdgcn_rcpf(x); }

#if __has_builtin(__builtin_amdgcn_exp2f)
__device__ __forceinline__ float ex2(float x) { return __builtin_amdgcn_exp2f(x); }
#define EXS 1.44269504f
#else
__device__ __forceinline__ float ex2(float x) { return __expf(x); }
#define EXS 1.0f
#endif

// LSTM cell update, 5 exp + 4 rcp, NaN-safe (tanh(c') via 1-2/(E+1); E=inf -> 0).
// Biases pre-folded & pre-scaled: bsc = { -EXS*bi, -EXS*bf, 2*EXS*bg, -EXS*bo }.
__device__ __forceinline__ float cellEW(float pi, float pf, float pg, float po,
                                        float4 bsc, float& c) {
    float A = ex2(fmaf(pf, -EXS, bsc.y));
    float B = ex2(fmaf(pi, -EXS, bsc.x));
    float C = ex2(fmaf(pg, 2.f * EXS, bsc.z));
    float ra = fr(1.f + A);
    float rb = fr((1.f + B) * (C + 1.f));
    float cn = fmaf(c, ra, (C - 1.f) * rb);
    c = cn;
    float D = ex2(fmaf(po, -EXS, bsc.w));
    float E = ex2(2.f * EXS * cn);
    float rd = fr(1.f + D);
    float re = fr(E + 1.f);
    return rd * fmaf(-2.f, re, 1.f);
}

__device__ __forceinline__ f16x8 cvt8(const float* p) {
    f16x8 r;
#pragma unroll
    for (int e = 0; e < 8; ++e) r[e] = (f16_t)p[e];
    return r;
}

// x A-fragment: k = 0..3 (lq==0, e<4) and valid rows (lc<8) only.
__device__ __forceinline__ f16x8 buildxf(float4 xq, int lq, int lc) {
    float v[4] = {xq.x, xq.y, xq.z, xq.w};
    f16x8 r;
#pragma unroll
    for (int e = 0; e < 8; ++e)
        r[e] = (e < 4 && lq == 0 && lc < 8) ? (f16_t)v[e] : (f16_t)0.f;
    return r;
}

// MFMA 16x16x32 f16 lane maps (verified R2-R5):
//   A[m][k]: lane l -> m = l%16, k = (l/16)*8 + e
//   B[k][n]: lane l -> n = l%16, k = (l/16)*8 + e
//   D[m][n]: lane l -> n = l%16, m = (l/16)*4 + q
// h-frag plane: f16 addr = kt*512 + chunk*8 + e; read chunk = l ^ (l>>4);
// write for h(m,k): lp = m + 16*((k&31)>>3), chunk = lp ^ ((k&31)>>3)  (verified pair).
//
// MM=8: A rows 8-15 are zero -> D rows 8-15 zero, discarded. Valid cells all live in
// lanes 0-31 (m = lq*4+q < 8 <=> lq < 2), so EW REDISTRIBUTES: lanes >=32 pull q=2,3
// from lane-32 via shfl -> every lane owns 2 cells: m = (lq&1)*4 + (l>>5)*2 + qq.

__global__ __launch_bounds__(512, 4) void lstm_f16o(
    const float* __restrict__ x,
    const float* __restrict__ w_ih0, const float* __restrict__ w_hh0,
    const float* __restrict__ b_ih0, const float* __restrict__ b_hh0,
    const float* __restrict__ w_ih1, const float* __restrict__ w_hh1,
    const float* __restrict__ b_ih1, const float* __restrict__ b_hh1,
    const float* __restrict__ fc1_w, const float* __restrict__ fc1_b,
    const float* __restrict__ fc2_w, const float* __restrict__ fc2_b,
    float* __restrict__ out)
{
    __shared__ __align__(16) unsigned hpl[2][2][512];   // [buf][layer] h-frag planes
    __shared__ __align__(16) float sH[MM * 68];
    __shared__ float sY[MM * 34];

    const int tid = threadIdx.x;
    const int l   = tid & 63;
    const int wv  = tid >> 6;
    const int rbase = blockIdx.x * MM;

    const int lc = l & 15;
    const int lq = l >> 4;
    const int chunk = l ^ lq;

    const bool isL1 = (wv >= 4);
    const int  ht   = wv & 3;
    const int  hidx = ht * 16 + lc;

    // write-side addressing for h(m, hidx)
    const int ktw = hidx >> 5;
    const int kk  = hidx & 31;
    const int ew  = kk & 7;
    const int kb  = kk >> 3;
    // EW cell-row base after redistribution
    const int mb  = (lq & 1) * 4 + (l >> 5) * 2;

    // ---------------- prologue: B-fragments -> registers ----------------
    f16x8 wA[4][2], wB[4][2], wx[4];
    float4 bsc;
    {
        float bi = 0, bf = 0, bg = 0, bo = 0;
#pragma unroll
        for (int g = 0; g < 4; ++g) {
            const int ga = g * 64 + hidx;
            float b;
            if (isL1) {
#pragma unroll
                for (int kt = 0; kt < 2; ++kt)
                    wA[g][kt] = cvt8(w_hh0 + ga * 64 + kt * 32 + lq * 8);
                float4 w4 = *(const float4*)(w_ih0 + ga * 4);
                wx[g] = buildxf(w4, lq, lc);   // (row-mask irrelevant for B; harmless)
                b = b_ih0[ga] + b_hh0[ga];
            } else {
#pragma unroll
                for (int kt = 0; kt < 2; ++kt) {
                    wA[g][kt] = cvt8(w_ih1 + ga * 64 + kt * 32 + lq * 8);
                    wB[g][kt] = cvt8(w_hh1 + ga * 64 + kt * 32 + lq * 8);
                }
                b = b_ih1[ga] + b_hh1[ga];
            }
            if (g == 0) bi = b; else if (g == 1) bf = b; else if (g == 2) bg = b; else bo = b;
        }
        bsc = make_float4(-EXS * bi, -EXS * bf, 2.f * EXS * bg, -EXS * bo);
    }
    // B-frag for x must NOT be row-masked; rebuild without lc mask for L1:
    if (isL1) {
#pragma unroll
        for (int g = 0; g < 4; ++g) {
            const int ga = g * 64 + hidx;
            float4 w4 = *(const float4*)(w_ih0 + ga * 4);
            float v[4] = {w4.x, w4.y, w4.z, w4.w};
#pragma unroll
            for (int e = 0; e < 8; ++e)
                wx[g][e] = (e < 4 && lq == 0) ? (f16_t)v[e] : (f16_t)0.f;
        }
    }

    for (int i = tid; i < 2 * 2 * 512; i += 512) ((unsigned*)hpl)[i] = 0;

    float c_st[2] = {0.f, 0.f};

    const float4* xg = (const float4*)x;
    const size_t xrow = (size_t)(rbase + (lc & 7)) * TT;
    float4 xq0 = make_float4(0, 0, 0, 0), xq = make_float4(0, 0, 0, 0);
    if (isL1) { xq0 = xg[xrow + 0]; xq = xg[xrow + 1]; }

    __syncthreads();

    const int srcl = l & 31;

    // ---------------- prime: h1(0) from x(0) only ----------------
    if (isL1) {
        f16x8 xf = buildxf(xq0, lq, lc);
        f32x4 a[4];
#pragma unroll
        for (int g = 0; g < 4; ++g) {
#pragma unroll
            for (int q = 0; q < 4; ++q) a[g][q] = 0.f;
            a[g] = MFMA16(xf, wx[g], a[g]);
        }
        float pre[4][2];
#pragma unroll
        for (int g = 0; g < 4; ++g) {
            float s2 = __shfl(a[g][2], srcl);
            float s3 = __shfl(a[g][3], srcl);
            pre[g][0] = (l < 32) ? a[g][0] : s2;
            pre[g][1] = (l < 32) ? a[g][1] : s3;
        }
        f16_t* dst = (f16_t*)hpl[0][0];
#pragma unroll
        for (int qq = 0; qq < 2; ++qq) {
            float hv = cellEW(pre[0][qq], pre[1][qq], pre[2][qq], pre[3][qq], bsc, c_st[qq]);
            const int lp = (mb + qq) + 16 * kb;
            dst[ktw * 512 + (lp ^ kb) * 8 + ew] = (f16_t)hv;
        }
    }
    __syncthreads();

    // ---------------- main loop: 1 barrier/step ----------------
    int cur = 0;
    for (int t = 0; t < TT; ++t) {
        f32x4 a[4];
        if (isL1) {
            if (t + 1 < TT) {
                const int tnext = (t + 2 < TT) ? t + 2 : TT - 1;
                float4 xq_new = xg[xrow + tnext];

                const f16_t* p1 = (const f16_t*)hpl[cur][0];
                f16x8 ah[2];
#pragma unroll
                for (int kt = 0; kt < 2; ++kt)
                    ah[kt] = *(const f16x8*)(p1 + kt * 512 + chunk * 8);
                f16x8 xf = buildxf(xq, lq, lc);

                __builtin_amdgcn_s_setprio(1);
#pragma unroll
                for (int g = 0; g < 4; ++g) {
#pragma unroll
                    for (int q = 0; q < 4; ++q) a[g][q] = 0.f;
                    a[g] = MFMA16(xf, wx[g], a[g]);
                    a[g] = MFMA16(ah[0], wA[g][0], a[g]);
                    a[g] = MFMA16(ah[1], wA[g][1], a[g]);
                }
                __builtin_amdgcn_s_setprio(0);

                float pre[4][2];
#pragma unroll
                for (int g = 0; g < 4; ++g) {
                    float s2 = __shfl(a[g][2], srcl);
                    float s3 = __shfl(a[g][3], srcl);
                    pre[g][0] = (l < 32) ? a[g][0] : s2;
                    pre[g][1] = (l < 32) ? a[g][1] : s3;
                }
                f16_t* dst = (f16_t*)hpl[cur ^ 1][0];
#pragma unroll
                for (int qq = 0; qq < 2; ++qq) {
                    float hv = cellEW(pre[0][qq], pre[1][qq], pre[2][qq], pre[3][qq], bsc, c_st[qq]);
                    const int lp = (mb + qq) + 16 * kb;
                    dst[ktw * 512 + (lp ^ kb) * 8 + ew] = (f16_t)hv;
                }
                xq = xq_new;
            }
        } else {
            const f16_t* p1 = (const f16_t*)hpl[cur][0];
            const f16_t* p2 = (const f16_t*)hpl[cur][1];
            f16x8 ah[2], ph[2];
#pragma unroll
            for (int kt = 0; kt < 2; ++kt) {
                ah[kt] = *(const f16x8*)(p1 + kt * 512 + chunk * 8);
                ph[kt] = *(const f16x8*)(p2 + kt * 512 + chunk * 8);
            }
            __builtin_amdgcn_s_setprio(1);
#pragma unroll
            for (int g = 0; g < 4; ++g) {
#pragma unroll
                for (int q = 0; q < 4; ++q) a[g][q] = 0.f;
                a[g] = MFMA16(ah[0], wA[g][0], a[g]);
                a[g] = MFMA16(ah[1], wA[g][1], a[g]);
                a[g] = MFMA16(ph[0], wB[g][0], a[g]);
                a[g] = MFMA16(ph[1], wB[g][1], a[g]);
            }
            __builtin_amdgcn_s_setprio(0);

            float pre[4][2];
#pragma unroll
            for (int g = 0; g < 4; ++g) {
                float s2 = __shfl(a[g][2], srcl);
                float s3 = __shfl(a[g][3], srcl);
                pre[g][0] = (l < 32) ? a[g][0] : s2;
                pre[g][1] = (l < 32) ? a[g][1] : s3;
            }
            f16_t* dst = (f16_t*)hpl[cur ^ 1][1];
            const bool last = (t == TT - 1);
#pragma unroll
            for (int qq = 0; qq < 2; ++qq) {
                float hv = cellEW(pre[0][qq], pre[1][qq], pre[2][qq], pre[3][qq], bsc, c_st[qq]);
                const int lp = (mb + qq) + 16 * kb;
                dst[ktw * 512 + (lp ^ kb) * 8 + ew] = (f16_t)hv;
                if (last) sH[(mb + qq) * 68 + hidx] = hv;
            }
        }
        cur ^= 1;
        __syncthreads();
    }

    // ---------------- FC head (8 rows) ----------------
    if (tid < MM * 32) {
        const int r = tid >> 5, mo = tid & 31;
        float s = fc1_b[mo];
#pragma unroll 8
        for (int k = 0; k < 64; ++k) s = fmaf(sH[r * 68 + k], fc1_w[mo * 64 + k], s);
        sY[r * 34 + mo] = fmaxf(s, 0.f);
    }
    __syncthreads();
    if (tid < MM * 2) {
        const int r = tid >> 1, o = tid & 1;
        float s = fc2_b[o];
#pragma unroll 8
        for (int mo = 0; mo < 32; ++mo) s = fmaf(sY[r * 34 + mo], fc2_w[o * 32 + mo], s);
        out[(size_t)(rbase + r) * 2 + o] = fmaxf(s, 0.f);
    }
}

extern "C" void kernel_launch(void* const* d_in, const int* in_sizes, int n_in,
                              void* d_out, int out_size, void* d_ws, size_t ws_size,
                              hipStream_t stream) {
    const float* x     = (const float*)d_in[0];
    const float* w_ih0 = (const float*)d_in[1];
    const float* w_hh0 = (const float*)d_in[2];
    const float* b_ih0 = (const float*)d_in[3];
    const float* b_hh0 = (const float*)d_in[4];
    const float* w_ih1 = (const float*)d_in[5];
    const float* w_hh1 = (const float*)d_in[6];
    const float* b_ih1 = (const float*)d_in[7];
    const float* b_hh1 = (const float*)d_in[8];
    const float* fc1_w = (const float*)d_in[9];
    const float* fc1_b = (const float*)d_in[10];
    const float* fc2_w = (const float*)d_in[11];
    const float* fc2_b = (const float*)d_in[12];
    float* out = (float*)d_out;

    const int nB   = in_sizes[0] / (TT * 4);   // 4096 rows
    const int grid = nB / MM;                  // 512 blocks -> 2/CU

    lstm_f16o<<<grid, 512, 0, stream>>>(x, w_ih0, w_hh0, b_ih0, b_hh0,
                                        w_ih1, w_hh1, b_ih1, b_hh1,
                                        fc1_w, fc1_b, fc2_w, fc2_b, out);
}

// Round 7
// 451.881 us; speedup vs baseline: 1.2729x; 1.2729x over previous
//
#include <hip/hip_runtime.h>

#define TT 512
#define MM 16      // batch rows per block

typedef _Float16 f16_t;
typedef f16_t f16x8 __attribute__((ext_vector_type(8)));
typedef float  f32x4 __attribute__((ext_vector_type(4)));

#define MFMA16(A, B, C) __builtin_amdgcn_mfma_f32_16x16x32_f16((A), (B), (C), 0, 0, 0)

__device__ __forceinline__ float fr(float x) { return __builtin_amdgcn_rcpf(x); }

#if __has_builtin(__builtin_amdgcn_exp2f)
__device__ __forceinline__ float ex2(float x) { return __builtin_amdgcn_exp2f(x); }
#define EXS 1.44269504f
#else
__device__ __forceinline__ float ex2(float x) { return __expf(x); }
#define EXS 1.0f
#endif

// LSTM cell update: 5 exp + 3 rcp.
// c' = c/(1+A) + (C-1)/((1+B)(C+1)) fused over one rcp (C bounded in practice,
// same exposure as R4-R6 which passed); h-path keeps the overflow-safe
// 1-2/(E+1) form since c' is the only unbounded input (E=inf -> re=0 -> tanh=1).
// Biases pre-folded & pre-scaled: bsc = { -EXS*bi, -EXS*bf, 2*EXS*bg, -EXS*bo }.
__device__ __forceinline__ float cellEW(float pi, float pf, float pg, float po,
                                        float4 bsc, float& c) {
    float A = ex2(fmaf(pf, -EXS, bsc.y));
    float B = ex2(fmaf(pi, -EXS, bsc.x));
    float C = ex2(fmaf(pg, 2.f * EXS, bsc.z));
    float u   = (1.f + B) * (C + 1.f);
    float oa  = 1.f + A;
    float num = fmaf(c * oa, u * fr(oa), oa * (C - 1.f));  // = c*u + (1+A)(C-1), keep 1 rcp form
    // NOTE: simpler exact form below (used): num = c*u + oa*(C-1), den = oa*u
    float cn;
    {
        float nm = fmaf(c, u, oa * (C - 1.f));
        float den = oa * u;
        cn = nm * fr(den);
    }
    (void)num;
    c = cn;
    float D = ex2(fmaf(po, -EXS, bsc.w));
    float E = ex2(2.f * EXS * cn);
    float rd = fr(1.f + D);
    float re = fr(E + 1.f);
    return rd * fmaf(-2.f, re, 1.f);
}

__device__ __forceinline__ f16x8 cvt8(const float* p) {
    f16x8 r;
#pragma unroll
    for (int e = 0; e < 8; ++e) r[e] = (f16_t)p[e];
    return r;
}

// x A-fragment: only k = 0..3 (lq==0, e<4) valid, rest zero.
__device__ __forceinline__ f16x8 buildxf(float4 xq, int lq) {
    float v[4] = {xq.x, xq.y, xq.z, xq.w};
    f16x8 r;
#pragma unroll
    for (int e = 0; e < 8; ++e) r[e] = (e < 4 && lq == 0) ? (f16_t)v[e] : (f16_t)0.f;
    return r;
}

// MFMA 16x16x32 f16 lane maps (verified R2-R6):
//   A[m][k]: lane l -> m = l%16, k = (l/16)*8 + e
//   B[k][n]: lane l -> n = l%16, k = (l/16)*8 + e
//   D[m][n]: lane l -> n = l%16, m = (l/16)*4 + q
// h-frag plane: f16 addr = kt*512 + chunk*8 + e; read chunk = l ^ (l>>4);
// write for h(m,k): lp = m + 16*((k&31)>>3), chunk = lp ^ ((k&31)>>3) (verified pair).
//
// Half-step pipeline (2 barriers/step, one MFMA-wave + one EW-wave per SIMD per half):
//   H1: L1 (waves 4-7): MFMA gates1(t+1) from h1(t)[p];  L2 (waves 0-3): EW gates2(t-1) -> h2(t-1)
//   H2: L1: EW gates1(t+1) -> h1(t+1)[p^1];              L2: MFMA gates2(t) from h1(t)[p] + h2(t-1)
// Buffers: hp1[2] double-buffered; hp2 single (write H1 of t+1 happens after last read H2 of t).

__global__ __launch_bounds__(512, 2) void lstm_hs(
    const float* __restrict__ x,
    const float* __restrict__ w_ih0, const float* __restrict__ w_hh0,
    const float* __restrict__ b_ih0, const float* __restrict__ b_hh0,
    const float* __restrict__ w_ih1, const float* __restrict__ w_hh1,
    const float* __restrict__ b_ih1, const float* __restrict__ b_hh1,
    const float* __restrict__ fc1_w, const float* __restrict__ fc1_b,
    const float* __restrict__ fc2_w, const float* __restrict__ fc2_b,
    float* __restrict__ out)
{
    __shared__ __align__(16) unsigned hp1[2][512];   // h1 frag planes (double buffer)
    __shared__ __align__(16) unsigned hp2[512];      // h2 frag plane (single)
    __shared__ __align__(16) float sH[MM * 68];
    __shared__ float sY[MM * 34];

    const int tid = threadIdx.x;
    const int l   = tid & 63;
    const int wv  = tid >> 6;
    const int rbase = blockIdx.x * MM;

    const int lc = l & 15;
    const int lq = l >> 4;
    const int chunk = l ^ lq;

    const bool isL1 = (wv >= 4);
    const int  ht   = wv & 3;
    const int  hidx = ht * 16 + lc;

    // write-side addressing for h(m = lq*4+q, hidx)
    const int ktw = hidx >> 5;
    const int kk  = hidx & 31;
    const int ew  = kk & 7;
    const int kb  = kk >> 3;

    // ---------------- prologue: B-fragments -> registers ----------------
    f16x8 wA[4][2], wB[4][2], wx[4];
    float bb[4];
#pragma unroll
    for (int g = 0; g < 4; ++g) {
        const int ga = g * 64 + hidx;
        if (isL1) {
#pragma unroll
            for (int kt = 0; kt < 2; ++kt)
                wA[g][kt] = cvt8(w_hh0 + ga * 64 + kt * 32 + lq * 8);
            float4 w4 = *(const float4*)(w_ih0 + ga * 4);
            wx[g] = buildxf(w4, lq);
            bb[g] = b_ih0[ga] + b_hh0[ga];
        } else {
#pragma unroll
            for (int kt = 0; kt < 2; ++kt) {
                wA[g][kt] = cvt8(w_ih1 + ga * 64 + kt * 32 + lq * 8);
                wB[g][kt] = cvt8(w_hh1 + ga * 64 + kt * 32 + lq * 8);
            }
            bb[g] = b_ih1[ga] + b_hh1[ga];
        }
    }
    const float4 bsc = make_float4(-EXS * bb[0], -EXS * bb[1],
                                   2.f * EXS * bb[2], -EXS * bb[3]);

    hp2[tid] = 0;                       // h2(-1) = 0

    float c_st[4] = {0.f, 0.f, 0.f, 0.f};

    const float4* xg = (const float4*)x;
    const size_t xrow = (size_t)(rbase + lc) * TT;
    float4 xq = make_float4(0, 0, 0, 0), xq0 = make_float4(0, 0, 0, 0);
    if (isL1) { xq0 = xg[xrow + 0]; xq = xg[xrow + 1]; }

    __syncthreads();

    // ---------------- prime: h1(0) from x(0) only -> hp1[0] ----------------
    if (isL1) {
        f16x8 xf = buildxf(xq0, lq);
        f32x4 a[4];
#pragma unroll
        for (int g = 0; g < 4; ++g) {
#pragma unroll
            for (int q = 0; q < 4; ++q) a[g][q] = 0.f;
            a[g] = MFMA16(xf, wx[g], a[g]);
        }
        f16_t* dst = (f16_t*)hp1[0];
#pragma unroll
        for (int q = 0; q < 4; ++q) {
            float hv = cellEW(a[0][q], a[1][q], a[2][q], a[3][q], bsc, c_st[q]);
            const int lp = (lq * 4 + q) + 16 * kb;
            dst[ktw * 512 + (lp ^ kb) * 8 + ew] = (f16_t)hv;
        }
    }
    __syncthreads();

    // ---------------- main loop: 2 barriers/step, role-alternating halves ----------------
    int p = 0;
    f32x4 a2[4];    // L2 gate acc, set in H2(t), consumed in H1(t+1)
    for (int t = 0; t < TT; ++t) {
        f32x4 a1[4];
        // ======== H1 ========
        if (isL1) {
            if (t + 1 < TT) {
                const int tn = (t + 2 < TT) ? t + 2 : TT - 1;
                float4 xn = xg[xrow + tn];

                const f16_t* p1 = (const f16_t*)hp1[p];
                f16x8 ah[2];
#pragma unroll
                for (int kt = 0; kt < 2; ++kt)
                    ah[kt] = *(const f16x8*)(p1 + kt * 512 + chunk * 8);
                f16x8 xf = buildxf(xq, lq);

                __builtin_amdgcn_s_setprio(1);
#pragma unroll
                for (int g = 0; g < 4; ++g) {
#pragma unroll
                    for (int q = 0; q < 4; ++q) a1[g][q] = 0.f;
                    a1[g] = MFMA16(xf, wx[g], a1[g]);
                    a1[g] = MFMA16(ah[0], wA[g][0], a1[g]);
                    a1[g] = MFMA16(ah[1], wA[g][1], a1[g]);
                }
                __builtin_amdgcn_s_setprio(0);
                xq = xn;
            }
        } else {
            if (t >= 1) {
                f16_t* dst = (f16_t*)hp2;
#pragma unroll
                for (int q = 0; q < 4; ++q) {
                    float hv = cellEW(a2[0][q], a2[1][q], a2[2][q], a2[3][q], bsc, c_st[q]);
                    const int lp = (lq * 4 + q) + 16 * kb;
                    dst[ktw * 512 + (lp ^ kb) * 8 + ew] = (f16_t)hv;
                }
            }
        }
        __syncthreads();

        // ======== H2 ========
        if (isL1) {
            if (t + 1 < TT) {
                f16_t* dst = (f16_t*)hp1[p ^ 1];
#pragma unroll
                for (int q = 0; q < 4; ++q) {
                    float hv = cellEW(a1[0][q], a1[1][q], a1[2][q], a1[3][q], bsc, c_st[q]);
                    const int lp = (lq * 4 + q) + 16 * kb;
                    dst[ktw * 512 + (lp ^ kb) * 8 + ew] = (f16_t)hv;
                }
            }
        } else {
            const f16_t* p1 = (const f16_t*)hp1[p];
            const f16_t* p2 = (const f16_t*)hp2;
            f16x8 ah[2], ph[2];
#pragma unroll
            for (int kt = 0; kt < 2; ++kt) {
                ah[kt] = *(const f16x8*)(p1 + kt * 512 + chunk * 8);
                ph[kt] = *(const f16x8*)(p2 + kt * 512 + chunk * 8);
            }
            __builtin_amdgcn_s_setprio(1);
#pragma unroll
            for (int g = 0; g < 4; ++g) {
#pragma unroll
                for (int q = 0; q < 4; ++q) a2[g][q] = 0.f;
                a2[g] = MFMA16(ah[0], wA[g][0], a2[g]);
                a2[g] = MFMA16(ah[1], wA[g][1], a2[g]);
                a2[g] = MFMA16(ph[0], wB[g][0], a2[g]);
                a2[g] = MFMA16(ph[1], wB[g][1], a2[g]);
            }
            __builtin_amdgcn_s_setprio(0);
        }
        p ^= 1;
        __syncthreads();
    }

    // ---------------- epilogue: EW2 on gates2(511) -> h2(511) -> sH ----------------
    if (!isL1) {
#pragma unroll
        for (int q = 0; q < 4; ++q) {
            float hv = cellEW(a2[0][q], a2[1][q], a2[2][q], a2[3][q], bsc, c_st[q]);
            sH[(lq * 4 + q) * 68 + hidx] = hv;
        }
    }
    __syncthreads();

    // ---------------- FC head ----------------
    {
        const int r = tid >> 5, mo = tid & 31;
        float s = fc1_b[mo];
#pragma unroll 8
        for (int k = 0; k < 64; ++k) s = fmaf(sH[r * 68 + k], fc1_w[mo * 64 + k], s);
        sY[r * 34 + mo] = fmaxf(s, 0.f);
    }
    __syncthreads();
    if (tid < 32) {
        const int r = tid >> 1, o = tid & 1;
        float s = fc2_b[o];
#pragma unroll 8
        for (int mo = 0; mo < 32; ++mo) s = fmaf(sY[r * 34 + mo], fc2_w[o * 32 + mo], s);
        out[(size_t)(rbase + r) * 2 + o] = fmaxf(s, 0.f);
    }
}

extern "C" void kernel_launch(void* const* d_in, const int* in_sizes, int n_in,
                              void* d_out, int out_size, void* d_ws, size_t ws_size,
                              hipStream_t stream) {
    const float* x     = (const float*)d_in[0];
    const float* w_ih0 = (const float*)d_in[1];
    const float* w_hh0 = (const float*)d_in[2];
    const float* b_ih0 = (const float*)d_in[3];
    const float* b_hh0 = (const float*)d_in[4];
    const float* w_ih1 = (const float*)d_in[5];
    const float* w_hh1 = (const float*)d_in[6];
    const float* b_ih1 = (const float*)d_in[7];
    const float* b_hh1 = (const float*)d_in[8];
    const float* fc1_w = (const float*)d_in[9];
    const float* fc1_b = (const float*)d_in[10];
    const float* fc2_w = (const float*)d_in[11];
    const float* fc2_b = (const float*)d_in[12];
    float* out = (float*)d_out;

    const int nB   = in_sizes[0] / (TT * 4);   // 4096 rows
    const int grid = nB / MM;                  // 256 blocks -> 1/CU

    lstm_hs<<<grid, 512, 0, stream>>>(x, w_ih0, w_hh0, b_ih0, b_hh0,
                                      w_ih1, w_hh1, b_ih1, b_hh1,
                                      fc1_w, fc1_b, fc2_w, fc2_b, out);
}